// Round 5
// baseline (720.157 us; speedup 1.0000x reference)
//
#include <hip/hip_runtime.h>
#include <stdint.h>
#include <math.h>

#define NEG 0.2f
#define TINYF 1.1754943508222875e-38f

typedef float f4 __attribute__((ext_vector_type(4)));
typedef float f2 __attribute__((ext_vector_type(2)));

// ---------------- Threefry-2x32-20 (matches JAX) ----------------
__host__ __device__ inline void threefry2x32(uint32_t k0, uint32_t k1,
                                             uint32_t x0, uint32_t x1,
                                             uint32_t* o0, uint32_t* o1) {
  uint32_t ks0 = k0, ks1 = k1, ks2 = k0 ^ k1 ^ 0x1BD11BDAu;
  x0 += ks0; x1 += ks1;
#define RR(r) { x0 += x1; x1 = (x1 << (r)) | (x1 >> (32 - (r))); x1 ^= x0; }
  RR(13) RR(15) RR(26) RR(6)
  x0 += ks1; x1 += ks2 + 1u;
  RR(17) RR(29) RR(16) RR(24)
  x0 += ks2; x1 += ks0 + 2u;
  RR(13) RR(15) RR(26) RR(6)
  x0 += ks0; x1 += ks1 + 3u;
  RR(17) RR(29) RR(16) RR(24)
  x0 += ks1; x1 += ks2 + 4u;
  RR(13) RR(15) RR(26) RR(6)
  x0 += ks2; x1 += ks0 + 5u;
#undef RR
  *o0 = x0; *o1 = x1;
}

// jax_threefry_partitionable=True random_bits, bit_width=32:
//   bits[i] = o0 ^ o1 of TF(key, (0, i))   [verified exact: R3-R9 pass]
__device__ inline float gumbel_part(uint32_t ka, uint32_t kb, uint32_t i) {
  uint32_t o0, o1;
  threefry2x32(ka, kb, 0u, i, &o0, &o1);
  uint32_t bits = o0 ^ o1;
  float f = __uint_as_float((bits >> 9) | 0x3f800000u) - 1.0f;
  float u = fmaxf(TINYF, f + TINYF);
  return -logf(-logf(u));
}

// ---------------- CSR build ----------------
__global__ void count_kernel(const int* __restrict__ ei, int E, int* __restrict__ counts) {
  int e = blockIdx.x * blockDim.x + threadIdx.x;
  if (e < E) atomicAdd(&counts[ei[E + e]], 1);
}

// parallel scan, 3 phases
#define SCB 256
__global__ __launch_bounds__(256) void scan_partial_kernel(const int* __restrict__ counts,
    int N, int chunk, int* __restrict__ bsum) {
  int b = blockIdx.x;
  int s0 = b * chunk, s1 = s0 + chunk; if (s1 > N) s1 = N;
  int tid = threadIdx.x;
  int v = 0;
  for (int i = s0 + tid; i < s1; i += 256) v += counts[i];
  __shared__ int red[256];
  red[tid] = v; __syncthreads();
  for (int s = 128; s; s >>= 1) { if (tid < s) red[tid] += red[tid + s]; __syncthreads(); }
  if (tid == 0) bsum[b] = red[0];
}

__global__ __launch_bounds__(256) void scan_offsets_kernel(const int* __restrict__ bsum,
    int* __restrict__ boff, int* __restrict__ row_start, int N) {
  int tid = threadIdx.x; int lane = tid & 63; int wv = tid >> 6;
  __shared__ int wsum[4];
  int v = bsum[tid];
  int incl = v;
#pragma unroll
  for (int off = 1; off < 64; off <<= 1) {
    int t = __shfl_up(incl, off);
    if (lane >= off) incl += t;
  }
  if (lane == 63) wsum[wv] = incl;
  __syncthreads();
  if (tid == 0) {
    int s = 0;
    for (int k = 0; k < 4; k++) { int t = wsum[k]; wsum[k] = s; s += t; }
    row_start[N] = s;
  }
  __syncthreads();
  boff[tid] = wsum[wv] + incl - v;
}

__global__ __launch_bounds__(256) void scan_apply_kernel(const int* __restrict__ counts,
    const int* __restrict__ boff, int N, int chunk,
    int* __restrict__ row_start, int* __restrict__ cursor) {
  int b = blockIdx.x;
  int s0 = b * chunk, s1 = s0 + chunk; if (s1 > N) s1 = N;
  int tid = threadIdx.x; int lane = tid & 63; int wv = tid >> 6;
  __shared__ int wsum[4];
  __shared__ int tot_s;
  __shared__ int base_s;
  if (tid == 0) base_s = boff[b];
  __syncthreads();
  for (int c0 = s0; c0 < s1; c0 += 256) {
    int i = c0 + tid;
    int v = (i < s1) ? counts[i] : 0;
    int incl = v;
#pragma unroll
    for (int off = 1; off < 64; off <<= 1) {
      int t = __shfl_up(incl, off);
      if (lane >= off) incl += t;
    }
    if (lane == 63) wsum[wv] = incl;
    __syncthreads();
    if (tid == 0) {
      int s = 0;
      for (int k = 0; k < 4; k++) { int t = wsum[k]; wsum[k] = s; s += t; }
      tot_s = s;
    }
    __syncthreads();
    int base = base_s;
    int excl = base + wsum[wv] + incl - v;
    if (i < s1) { row_start[i] = excl; cursor[i] = excl; }
    __syncthreads();
    if (tid == 0) base_s = base + tot_s;
    __syncthreads();
  }
}

// scatter: src_csr + dst_csr + ea permuted into CSR order
__global__ void scatter_kernel(const int* __restrict__ ei, const float* __restrict__ ea,
                               int E, int* __restrict__ cursor,
                               int* __restrict__ src_csr, int* __restrict__ dst_csr,
                               float* __restrict__ ea_csr) {
  int e = blockIdx.x * blockDim.x + threadIdx.x;
  if (e < E) {
    int d = ei[E + e];
    int p = atomicAdd(&cursor[d], 1);
    src_csr[p] = ei[e];
    dst_csr[p] = d;
    const float4* s4 = (const float4*)&ea[(size_t)e * 16];
    float4* d4 = (float4*)&ea_csr[(size_t)p * 16];
    float4 t0 = s4[0], t1 = s4[1], t2 = s4[2], t3 = s4[3];
    d4[0] = t0; d4[1] = t1; d4[2] = t2; d4[3] = t3;
  }
}

// ---------------- h = X @ W (128x128) + b ----------------
__global__ __launch_bounds__(256) void gemm128_kernel(const float* __restrict__ X,
    const float* __restrict__ W, const float* __restrict__ bias,
    float* __restrict__ out, int M) {
  __shared__ float xs[128][33];
  int row0 = blockIdx.x * 32;
  int tid = threadIdx.x;
  for (int idx = tid; idx < 32 * 128; idx += 256) {
    int r = idx >> 7;
    int k = idx & 127;
    int row = row0 + r;
    xs[k][r] = (row < M) ? X[(size_t)row * 128 + k] : 0.0f;
  }
  __syncthreads();
  int tc = tid & 31, tr = tid >> 5;
  int c0 = tc * 4, r0 = tr * 4;
  float acc[4][4] = {};
#pragma unroll 4
  for (int k = 0; k < 128; k++) {
    float4 w = *(const float4*)&W[k * 128 + c0];
    float x0 = xs[k][r0], x1 = xs[k][r0 + 1], x2 = xs[k][r0 + 2], x3 = xs[k][r0 + 3];
    acc[0][0] += x0 * w.x; acc[0][1] += x0 * w.y; acc[0][2] += x0 * w.z; acc[0][3] += x0 * w.w;
    acc[1][0] += x1 * w.x; acc[1][1] += x1 * w.y; acc[1][2] += x1 * w.z; acc[1][3] += x1 * w.w;
    acc[2][0] += x2 * w.x; acc[2][1] += x2 * w.y; acc[2][2] += x2 * w.z; acc[2][3] += x2 * w.w;
    acc[3][0] += x3 * w.x; acc[3][1] += x3 * w.y; acc[3][2] += x3 * w.z; acc[3][3] += x3 * w.w;
  }
  float4 b4 = *(const float4*)&bias[c0];
  for (int r = 0; r < 4; r++) {
    int row = row0 + r0 + r;
    if (row < M) {
      float4 o;
      o.x = acc[r][0] + b4.x; o.y = acc[r][1] + b4.y;
      o.z = acc[r][2] + b4.z; o.w = acc[r][3] + b4.w;
      *(float4*)&out[(size_t)row * 128 + c0] = o;
    }
  }
}

// ---------------- h3 = latent @ Wl3 (128x32) + b ----------------
__global__ __launch_bounds__(256) void gemm32_kernel(const float* __restrict__ X,
    const float* __restrict__ W, const float* __restrict__ bias,
    float* __restrict__ out, int M) {
  int t = blockIdx.x * 256 + threadIdx.x;
  int node = t >> 5, c = t & 31;
  if (node >= M) return;
  const float4* xp = (const float4*)&X[(size_t)node * 128];
  float acc = 0.f;
#pragma unroll
  for (int q = 0; q < 32; q++) {
    float4 x4 = xp[q];
    acc += x4.x * W[(q * 4 + 0) * 32 + c] + x4.y * W[(q * 4 + 1) * 32 + c]
         + x4.z * W[(q * 4 + 2) * 32 + c] + x4.w * W[(q * 4 + 3) * 32 + c];
  }
  out[(size_t)node * 32 + c] = acc + bias[c];
}

// ---------------- h2 = latent @ Wl2 (128x1) + b ----------------
__global__ __launch_bounds__(256) void gemv_kernel(const float* __restrict__ X,
    const float* __restrict__ w, const float* __restrict__ b0,
    float* __restrict__ out, int M) {
  int wv = (blockIdx.x * 256 + threadIdx.x) >> 6;
  int lane = threadIdx.x & 63;
  if (wv >= M) return;
  float2 xv = *(const float2*)&X[(size_t)wv * 128 + lane * 2];
  float2 wvv = *(const float2*)&w[lane * 2];
  float v = xv.x * wvv.x + xv.y * wvv.y;
#pragma unroll
  for (int off = 32; off; off >>= 1) v += __shfl_xor(v, off);
  if (lane == 0) out[wv] = v + b0[0];
}

// ---------------- P1: edge-parallel layer-1 scores ----------------
// Half-wave per EDGE, EPH contiguous edges per half-wave, 2-edge ILP unroll.
// No loop-carried deps: pure throughput. w = exp(score) (fixed base; exact per R3).
#define EPH 8
__global__ __launch_bounds__(256, 3) void edge_score1_kernel(
    const float* __restrict__ h,
    const int* __restrict__ src_csr, const int* __restrict__ dst_csr,
    const float* __restrict__ ea_csr,
    const float* __restrict__ We, const float* __restrict__ att,
    float* __restrict__ w_csr, int E) {
  int tid = threadIdx.x;
  int lane = tid & 31;
  int hw = (blockIdx.x * 256 + tid) >> 5;
  int e0 = hw * EPH;
  if (e0 >= E) return;
  int e1 = e0 + EPH; if (e1 > E) e1 = E;
  int c4 = lane * 4;
  f4 wr0  = *(const f4*)&We[0  * 128 + c4];
  f4 wr1  = *(const f4*)&We[1  * 128 + c4];
  f4 wr2  = *(const f4*)&We[2  * 128 + c4];
  f4 wr3  = *(const f4*)&We[3  * 128 + c4];
  f4 wr4  = *(const f4*)&We[4  * 128 + c4];
  f4 wr5  = *(const f4*)&We[5  * 128 + c4];
  f4 wr6  = *(const f4*)&We[6  * 128 + c4];
  f4 wr7  = *(const f4*)&We[7  * 128 + c4];
  f4 wr8  = *(const f4*)&We[8  * 128 + c4];
  f4 wr9  = *(const f4*)&We[9  * 128 + c4];
  f4 wr10 = *(const f4*)&We[10 * 128 + c4];
  f4 wr11 = *(const f4*)&We[11 * 128 + c4];
  f4 wr12 = *(const f4*)&We[12 * 128 + c4];
  f4 wr13 = *(const f4*)&We[13 * 128 + c4];
  f4 wr14 = *(const f4*)&We[14 * 128 + c4];
  f4 wr15 = *(const f4*)&We[15 * 128 + c4];
  f4 attv = *(const f4*)&att[c4];
  for (int e = e0; e < e1; e += 2) {
    int eB = e + 1;
    int hasB = (eB < e1);
    int eBc = hasB ? eB : e;
    int sA = src_csr[e];   int dA = dst_csr[e];
    int sB = src_csr[eBc]; int dB = dst_csr[eBc];
    f4 hjA = *(const f4*)&h[(size_t)sA * 128 + c4];
    f4 hiA = *(const f4*)&h[(size_t)dA * 128 + c4];
    f4 hjB = *(const f4*)&h[(size_t)sB * 128 + c4];
    f4 hiB = *(const f4*)&h[(size_t)dB * 128 + c4];
    const f4* eAp = (const f4*)&ea_csr[(size_t)e * 16];
    const f4* eBp = (const f4*)&ea_csr[(size_t)eBc * 16];
    f4 a0 = eAp[0], a1 = eAp[1], a2 = eAp[2], a3 = eAp[3];
    f4 b0 = eBp[0], b1 = eBp[1], b2 = eBp[2], b3 = eBp[3];
    f4 vA = hiA + hjA;
    f4 vB = hiB + hjB;
    vA += a0.x * wr0  + a0.y * wr1  + a0.z * wr2  + a0.w * wr3;
    vB += b0.x * wr0  + b0.y * wr1  + b0.z * wr2  + b0.w * wr3;
    vA += a1.x * wr4  + a1.y * wr5  + a1.z * wr6  + a1.w * wr7;
    vB += b1.x * wr4  + b1.y * wr5  + b1.z * wr6  + b1.w * wr7;
    vA += a2.x * wr8  + a2.y * wr9  + a2.z * wr10 + a2.w * wr11;
    vB += b2.x * wr8  + b2.y * wr9  + b2.z * wr10 + b2.w * wr11;
    vA += a3.x * wr12 + a3.y * wr13 + a3.z * wr14 + a3.w * wr15;
    vB += b3.x * wr12 + b3.y * wr13 + b3.z * wr14 + b3.w * wr15;
    vA.x = vA.x >= 0.f ? vA.x : NEG * vA.x;
    vA.y = vA.y >= 0.f ? vA.y : NEG * vA.y;
    vA.z = vA.z >= 0.f ? vA.z : NEG * vA.z;
    vA.w = vA.w >= 0.f ? vA.w : NEG * vA.w;
    vB.x = vB.x >= 0.f ? vB.x : NEG * vB.x;
    vB.y = vB.y >= 0.f ? vB.y : NEG * vB.y;
    vB.z = vB.z >= 0.f ? vB.z : NEG * vB.z;
    vB.w = vB.w >= 0.f ? vB.w : NEG * vB.w;
    f4 pA = vA * attv;
    f4 pB = vB * attv;
    float scA = (pA.x + pA.y) + (pA.z + pA.w);
    float scB = (pB.x + pB.y) + (pB.z + pB.w);
#pragma unroll
    for (int off = 16; off; off >>= 1) {
      scA += __shfl_xor(scA, off);
      scB += __shfl_xor(scB, off);
    }
    float wA = __expf(fminf(scA, 60.f));
    float wB = __expf(fminf(scB, 60.f));
    if (lane == 0) {
      w_csr[e] = wA;
      if (hasB) w_csr[eB] = wB;
    }
  }
}

// ---------------- P2: node-parallel layer-1 aggregate (light body, 4-deep prefetch) ----------------
__global__ __launch_bounds__(256) void aggregate1_kernel(
    const float* __restrict__ h, const int* __restrict__ src_csr,
    const int* __restrict__ row_start, const float* __restrict__ w_csr,
    const float* __restrict__ bias, float* __restrict__ out, int N) {
  int tid = threadIdx.x;
  int hw = (blockIdx.x * 256 + tid) >> 5;
  int lane = tid & 31;
  if (hw >= N) return;
  int c4 = lane * 4;
  f4 bb = *(const f4*)&bias[c4];
  int start = row_start[hw];
  int deg = row_start[hw + 1] - start;
  if (deg == 0) {
    *(f4*)&out[(size_t)hw * 128 + c4] = bb;
    return;
  }
  int s_l = (lane < deg) ? src_csr[start + lane] : 0;
  int dcap = deg < 32 ? deg : 32;
  int dm1 = deg - 1;
  // prime 4-deep prefetch (clamped; tail prefetches are cache hits)
  int jc1 = dm1 < 1 ? dm1 : 1;
  int jc2 = dm1 < 2 ? dm1 : 2;
  int jc3 = dm1 < 3 ? dm1 : 3;
  int s0 = __shfl(s_l, 0, 32);
  int s1 = (jc1 < dcap) ? __shfl(s_l, jc1, 32) : src_csr[start + jc1];
  int s2 = (jc2 < dcap) ? __shfl(s_l, jc2, 32) : src_csr[start + jc2];
  int s3 = (jc3 < dcap) ? __shfl(s_l, jc3, 32) : src_csr[start + jc3];
  f4 p0 = *(const f4*)&h[(size_t)s0 * 128 + c4];
  float w0v = w_csr[start + 0];
  f4 p1 = *(const f4*)&h[(size_t)s1 * 128 + c4];
  float w1v = w_csr[start + jc1];
  f4 p2 = *(const f4*)&h[(size_t)s2 * 128 + c4];
  float w2v = w_csr[start + jc2];
  f4 p3 = *(const f4*)&h[(size_t)s3 * 128 + c4];
  float w3v = w_csr[start + jc3];
  f4 acc = (f4)0.f;
  float l = 0.f;
  for (int j = 0; j < deg; j++) {
    f4 cur = p0; float cw = w0v;
    p0 = p1; w0v = w1v;
    p1 = p2; w1v = w2v;
    p2 = p3; w2v = w3v;
    int jn = j + 4; if (jn > dm1) jn = dm1;
    int sn = (jn < dcap) ? __shfl(s_l, jn, 32) : src_csr[start + jn];
    w3v = w_csr[start + jn];
    p3 = *(const f4*)&h[(size_t)sn * 128 + c4];
    acc += cw * cur;
    l += cw;
  }
  float inv = 1.0f / (l + 1e-16f);
  *(f4*)&out[(size_t)hw * 128 + c4] = acc * inv + bb;
}

// ---------------- P1': edge-parallel layers-2+3 scores ----------------
// Quarter-wave (16 lanes) per edge, EPQ contiguous edges per quarter.
#define EPQ 8
__global__ __launch_bounds__(256, 3) void edge_score23_kernel(
    const float* __restrict__ h3, const float* __restrict__ h2,
    const int* __restrict__ src_csr, const int* __restrict__ dst_csr,
    const float* __restrict__ ea_csr,
    const float* __restrict__ We3, const float* __restrict__ att3,
    const float* __restrict__ We2v, const float* __restrict__ att2,
    float* __restrict__ w23, int E) {
  int tid = threadIdx.x;
  int l16 = tid & 15;
  int qw = (blockIdx.x * 256 + tid) >> 4;
  int e0 = qw * EPQ;
  if (e0 >= E) return;
  int e1 = e0 + EPQ; if (e1 > E) e1 = E;
  int c2 = l16 * 2;
  f2 w3r0  = *(const f2*)&We3[0  * 32 + c2];
  f2 w3r1  = *(const f2*)&We3[1  * 32 + c2];
  f2 w3r2  = *(const f2*)&We3[2  * 32 + c2];
  f2 w3r3  = *(const f2*)&We3[3  * 32 + c2];
  f2 w3r4  = *(const f2*)&We3[4  * 32 + c2];
  f2 w3r5  = *(const f2*)&We3[5  * 32 + c2];
  f2 w3r6  = *(const f2*)&We3[6  * 32 + c2];
  f2 w3r7  = *(const f2*)&We3[7  * 32 + c2];
  f2 w3r8  = *(const f2*)&We3[8  * 32 + c2];
  f2 w3r9  = *(const f2*)&We3[9  * 32 + c2];
  f2 w3r10 = *(const f2*)&We3[10 * 32 + c2];
  f2 w3r11 = *(const f2*)&We3[11 * 32 + c2];
  f2 w3r12 = *(const f2*)&We3[12 * 32 + c2];
  f2 w3r13 = *(const f2*)&We3[13 * 32 + c2];
  f2 w3r14 = *(const f2*)&We3[14 * 32 + c2];
  f2 w3r15 = *(const f2*)&We3[15 * 32 + c2];
  float u = We2v[l16];
  f2 at3 = *(const f2*)&att3[c2];
  float a2s = att2[0];
  for (int e = e0; e < e1; e++) {
    int s = src_csr[e];
    int d = dst_csr[e];
    f2 hj = *(const f2*)&h3[(size_t)s * 32 + c2];
    f2 hi = *(const f2*)&h3[(size_t)d * 32 + c2];
    float h2s = h2[s];
    float h2i = h2[d];
    const float4* ep = (const float4*)&ea_csr[(size_t)e * 16];
    float4 c0 = ep[0], c1 = ep[1], cq = ep[2], c3 = ep[3];
    float eav = ea_csr[(size_t)e * 16 + l16];
    f2 v = hi + hj;
    v += c0.x * w3r0;  v += c0.y * w3r1;
    v += c0.z * w3r2;  v += c0.w * w3r3;
    v += c1.x * w3r4;  v += c1.y * w3r5;
    v += c1.z * w3r6;  v += c1.w * w3r7;
    v += cq.x * w3r8;  v += cq.y * w3r9;
    v += cq.z * w3r10; v += cq.w * w3r11;
    v += c3.x * w3r12; v += c3.y * w3r13;
    v += c3.z * w3r14; v += c3.w * w3r15;
    v.x = v.x >= 0.f ? v.x : NEG * v.x;
    v.y = v.y >= 0.f ? v.y : NEG * v.y;
    float t3 = v.x * at3.x + v.y * at3.y;
    float p2 = eav * u;
#pragma unroll
    for (int off = 8; off; off >>= 1) {
      t3 += __shfl_xor(t3, off);
      p2 += __shfl_xor(p2, off);
    }
    float v2 = h2i + h2s + p2;
    v2 = v2 >= 0.f ? v2 : NEG * v2;
    float t2 = v2 * a2s;
    float w3e = __expf(fminf(t3, 60.f));
    float w2e = __expf(fminf(t2, 60.f));
    if (l16 == 0) {
      f2 wp; wp.x = w3e; wp.y = w2e;
      *(f2*)&w23[(size_t)2 * e] = wp;
    }
  }
}

// ---------------- P2': node-parallel layers-2+3 aggregate ----------------
__global__ __launch_bounds__(256) void aggregate23_kernel(
    const float* __restrict__ h3, const float* __restrict__ h2,
    const int* __restrict__ src_csr, const int* __restrict__ row_start,
    const float* __restrict__ w23,
    const float* __restrict__ bias3, const float* __restrict__ bias2,
    float* __restrict__ out3, float* __restrict__ logits, int N) {
  int tid = threadIdx.x;
  int hw = (blockIdx.x * 256 + tid) >> 5;
  int lane = tid & 31;
  if (hw >= N) return;
  float b3v = bias3[lane];
  int start = row_start[hw];
  int deg = row_start[hw + 1] - start;
  if (deg == 0) {
    out3[(size_t)hw * 32 + lane] = b3v;
    if (lane == 0) logits[hw] = bias2[0];
    return;
  }
  int s_l = (lane < deg) ? src_csr[start + lane] : 0;
  int dcap = deg < 32 ? deg : 32;
  int dm1 = deg - 1;
  int jc1 = dm1 < 1 ? dm1 : 1;
  int jc2 = dm1 < 2 ? dm1 : 2;
  int jc3 = dm1 < 3 ? dm1 : 3;
  int s0 = __shfl(s_l, 0, 32);
  int s1 = (jc1 < dcap) ? __shfl(s_l, jc1, 32) : src_csr[start + jc1];
  int s2 = (jc2 < dcap) ? __shfl(s_l, jc2, 32) : src_csr[start + jc2];
  int s3 = (jc3 < dcap) ? __shfl(s_l, jc3, 32) : src_csr[start + jc3];
  float p0 = h3[(size_t)s0 * 32 + lane];
  float q0 = h2[s0];
  f2 w0v = *(const f2*)&w23[(size_t)2 * (start + 0)];
  float p1 = h3[(size_t)s1 * 32 + lane];
  float q1 = h2[s1];
  f2 w1v = *(const f2*)&w23[(size_t)2 * (start + jc1)];
  float p2 = h3[(size_t)s2 * 32 + lane];
  float q2 = h2[s2];
  f2 w2v = *(const f2*)&w23[(size_t)2 * (start + jc2)];
  float p3 = h3[(size_t)s3 * 32 + lane];
  float q3 = h2[s3];
  f2 w3v = *(const f2*)&w23[(size_t)2 * (start + jc3)];
  float acc3 = 0.f, l3 = 0.f, acc2 = 0.f, l2 = 0.f;
  for (int j = 0; j < deg; j++) {
    float cur3 = p0; float cur2 = q0; f2 cw = w0v;
    p0 = p1; q0 = q1; w0v = w1v;
    p1 = p2; q1 = q2; w1v = w2v;
    p2 = p3; q2 = q3; w2v = w3v;
    int jn = j + 4; if (jn > dm1) jn = dm1;
    int sn = (jn < dcap) ? __shfl(s_l, jn, 32) : src_csr[start + jn];
    w3v = *(const f2*)&w23[(size_t)2 * (start + jn)];
    p3 = h3[(size_t)sn * 32 + lane];
    q3 = h2[sn];
    acc3 += cw.x * cur3;
    l3 += cw.x;
    acc2 += cw.y * cur2;
    l2 += cw.y;
  }
  out3[(size_t)hw * 32 + lane] = acc3 / (l3 + 1e-16f) + b3v;
  if (lane == 0) logits[hw] = acc2 / (l2 + 1e-16f) + bias2[0];
}

// ---------------- node categorical: 64-block partial + 1-wave final ----------------
#define NSB 64
__global__ __launch_bounds__(256) void node_partial_kernel(const float* __restrict__ logits,
    int N, uint32_t ka, uint32_t kb,
    float* __restrict__ pB, int* __restrict__ pI,
    float* __restrict__ pM, float* __restrict__ pL) {
  int chunk = (N + NSB - 1) / NSB;
  int s0 = blockIdx.x * chunk;
  int s1 = s0 + chunk; if (s1 > N) s1 = N;
  int tid = threadIdx.x;
  float best = -INFINITY; int bi = 0x7fffffff;
  float m = -INFINITY, l = 0.f;
  for (int i = s0 + tid; i < s1; i += 256) {
    float lg = logits[i];
    float mn = fmaxf(m, lg);
    l = l * __expf(m - mn) + __expf(lg - mn);
    m = mn;
    float v = lg + gumbel_part(ka, kb, (uint32_t)i);
    if (v > best) { best = v; bi = i; }
  }
  __shared__ float sb[256], sm[256], sl[256];
  __shared__ int si[256];
  sb[tid] = best; si[tid] = bi; sm[tid] = m; sl[tid] = l;
  __syncthreads();
  for (int s = 128; s; s >>= 1) {
    if (tid < s) {
      if (sb[tid + s] > sb[tid] || (sb[tid + s] == sb[tid] && si[tid + s] < si[tid])) {
        sb[tid] = sb[tid + s]; si[tid] = si[tid + s];
      }
      float M = fmaxf(sm[tid], sm[tid + s]);
      float t0 = (sm[tid] == -INFINITY) ? 0.f : sl[tid] * __expf(sm[tid] - M);
      float t1 = (sm[tid + s] == -INFINITY) ? 0.f : sl[tid + s] * __expf(sm[tid + s] - M);
      sm[tid] = M; sl[tid] = t0 + t1;
    }
    __syncthreads();
  }
  if (tid == 0) { pB[blockIdx.x] = sb[0]; pI[blockIdx.x] = si[0]; pM[blockIdx.x] = sm[0]; pL[blockIdx.x] = sl[0]; }
}

__global__ __launch_bounds__(64) void node_final_kernel(const float* __restrict__ logits,
    const float* __restrict__ pB, const int* __restrict__ pI,
    const float* __restrict__ pM, const float* __restrict__ pL,
    float* __restrict__ scal) {
  int lane = threadIdx.x;
  float best = pB[lane]; int bi = pI[lane];
  float m = pM[lane]; float l = pL[lane];
#pragma unroll
  for (int off = 32; off; off >>= 1) {
    float ob = __shfl_xor(best, off); int oi = __shfl_xor(bi, off);
    if (ob > best || (ob == best && oi < bi)) { best = ob; bi = oi; }
    float om = __shfl_xor(m, off); float ol = __shfl_xor(l, off);
    float M = fmaxf(m, om);
    float t0 = (m == -INFINITY) ? 0.f : l * __expf(m - M);
    float t1 = (om == -INFINITY) ? 0.f : ol * __expf(om - M);
    m = M; l = t0 + t1;
  }
  if (lane == 0) {
    ((int*)scal)[0] = bi;
    scal[3] = logits[bi] - (m + logf(l));
  }
}

// ---------------- action categorical + output ----------------
__global__ __launch_bounds__(64) void action_kernel(const float* __restrict__ out3,
    const float* __restrict__ scal, uint32_t ka, uint32_t kb,
    float* __restrict__ dout, int out_size) {
  int lane = threadIdx.x;
  int sel = ((const int*)scal)[0];
  float v = -INFINITY, noisy = -INFINITY;
  if (lane < 32) {
    v = out3[(size_t)sel * 32 + lane];
    noisy = v + gumbel_part(ka, kb, (uint32_t)lane);
  }
  int idx = lane;
  float nv = noisy;
#pragma unroll
  for (int off = 32; off; off >>= 1) {
    float ov = __shfl_xor(nv, off);
    int oi = __shfl_xor(idx, off);
    if (ov > nv || (ov == nv && oi < idx)) { nv = ov; idx = oi; }
  }
  float vm = v;
#pragma unroll
  for (int off = 32; off; off >>= 1) vm = fmaxf(vm, __shfl_xor(vm, off));
  float ex = (lane < 32) ? expf(v - vm) : 0.f;
#pragma unroll
  for (int off = 32; off; off >>= 1) ex += __shfl_xor(ex, off);
  float vsel = __shfl(v, idx);
  if (lane == 0) {
    float action_lp = vsel - vm - logf(ex);
    dout[0] = (float)sel;
    dout[1] = (float)idx;
    dout[2] = scal[3] + action_lp;
  }
  for (int i = 3 + lane; i < out_size; i += 64) dout[i] = 0.f;
}

extern "C" void kernel_launch(void* const* d_in, const int* in_sizes, int n_in,
                              void* d_out, int out_size, void* d_ws, size_t ws_size,
                              hipStream_t stream) {
  const float* x     = (const float*)d_in[0];
  const int*   ei    = (const int*)d_in[1];
  const float* ea    = (const float*)d_in[2];
  const float* Wl1   = (const float*)d_in[3];
  const float* bl1   = (const float*)d_in[4];
  const float* We1   = (const float*)d_in[5];
  const float* att1  = (const float*)d_in[6];
  const float* bias1 = (const float*)d_in[7];
  const float* Wl2   = (const float*)d_in[8];
  const float* bl2   = (const float*)d_in[9];
  const float* We2   = (const float*)d_in[10];
  const float* att2  = (const float*)d_in[11];
  const float* bias2 = (const float*)d_in[12];
  const float* Wl3   = (const float*)d_in[13];
  const float* bl3   = (const float*)d_in[14];
  const float* We3   = (const float*)d_in[15];
  const float* att3  = (const float*)d_in[16];
  const float* bias3 = (const float*)d_in[17];
  int N = in_sizes[0] / 128;
  int E = in_sizes[1] / 2;
  float* out = (float*)d_out;

  char* p = (char*)d_ws;
  auto alloc = [&](size_t bytes) -> char* {
    char* r = p; p += (bytes + 255) & ~(size_t)255; return r;
  };
  float* h1      = (float*)alloc((size_t)N * 128 * 4);
  float* latent  = (float*)alloc((size_t)N * 128 * 4);
  float* h3      = (float*)alloc((size_t)N * 32 * 4);
  float* h2      = (float*)alloc((size_t)N * 4);
  float* logits  = (float*)alloc((size_t)N * 4);
  float* out3    = (float*)alloc((size_t)N * 32 * 4);
  int* counts    = (int*)alloc((size_t)N * 4);
  int* row_start = (int*)alloc((size_t)(N + 1) * 4);
  int* cursor    = (int*)alloc((size_t)N * 4);
  int* src_csr   = (int*)alloc((size_t)E * 4);
  int* dst_csr   = (int*)alloc((size_t)E * 4);
  float* ea_csr  = (float*)alloc((size_t)E * 16 * 4);
  float* w1_csr  = (float*)alloc((size_t)E * 4);
  float* w23_csr = (float*)alloc((size_t)E * 8);
  int* bsum      = (int*)alloc(SCB * 4);
  int* boff      = (int*)alloc(SCB * 4);
  float* pB      = (float*)alloc(NSB * 4);
  int*   pI      = (int*)alloc(NSB * 4);
  float* pM      = (float*)alloc(NSB * 4);
  float* pL      = (float*)alloc(NSB * 4);
  float* scal    = (float*)alloc(64);
  (void)ws_size; (void)n_in;

  // JAX PRNG (partitionable): key(42)=(0,42); subkey_i = TF(key,(0,i))
  uint32_t k1a, k1b, k2a, k2b;
  threefry2x32(0u, 42u, 0u, 0u, &k1a, &k1b);
  threefry2x32(0u, 42u, 0u, 1u, &k2a, &k2b);

  int chunk = (N + SCB - 1) / SCB;

  hipMemsetAsync(counts, 0, (size_t)N * 4, stream);
  count_kernel<<<(E + 255) / 256, 256, 0, stream>>>(ei, E, counts);
  scan_partial_kernel<<<SCB, 256, 0, stream>>>(counts, N, chunk, bsum);
  scan_offsets_kernel<<<1, 256, 0, stream>>>(bsum, boff, row_start, N);
  scan_apply_kernel<<<SCB, 256, 0, stream>>>(counts, boff, N, chunk, row_start, cursor);
  scatter_kernel<<<(E + 255) / 256, 256, 0, stream>>>(ei, ea, E, cursor, src_csr, dst_csr, ea_csr);

  gemm128_kernel<<<(N + 31) / 32, 256, 0, stream>>>(x, Wl1, bl1, h1, N);

  int hws1 = (E + EPH - 1) / EPH;
  edge_score1_kernel<<<(hws1 + 7) / 8, 256, 0, stream>>>(h1, src_csr, dst_csr, ea_csr,
                                                         We1, att1, w1_csr, E);
  aggregate1_kernel<<<(N + 7) / 8, 256, 0, stream>>>(h1, src_csr, row_start, w1_csr,
                                                     bias1, latent, N);

  gemm32_kernel<<<((size_t)N * 32 + 255) / 256, 256, 0, stream>>>(latent, Wl3, bl3, h3, N);
  gemv_kernel<<<(N + 3) / 4, 256, 0, stream>>>(latent, Wl2, bl2, h2, N);

  int qws = (E + EPQ - 1) / EPQ;
  edge_score23_kernel<<<(qws + 15) / 16, 256, 0, stream>>>(h3, h2, src_csr, dst_csr, ea_csr,
                                                           We3, att3, We2, att2, w23_csr, E);
  aggregate23_kernel<<<(N + 7) / 8, 256, 0, stream>>>(h3, h2, src_csr, row_start, w23_csr,
                                                      bias3, bias2, out3, logits, N);

  node_partial_kernel<<<NSB, 256, 0, stream>>>(logits, N, k1a, k1b, pB, pI, pM, pL);
  node_final_kernel<<<1, 64, 0, stream>>>(logits, pB, pI, pM, pL, scal);
  action_kernel<<<1, 64, 0, stream>>>(out3, scal, k2a, k2b, out, out_size);
}